// Round 3
// baseline (289.782 us; speedup 1.0000x reference)
//
#include <hip/hip_runtime.h>

typedef __bf16 bf16x8 __attribute__((ext_vector_type(8)));
typedef float f32x4 __attribute__((ext_vector_type(4)));

#define BATCH 4
#define SEQ   2048
#define DIM   1024
#define NH    16
#define HD    64
#define ECF   0.18033688f   // log2(e)/8 : folds 1/sqrt(64) into exp2

__device__ __forceinline__ unsigned short f2bf(float f) {
  union { float f; unsigned u; } v; v.f = f;
  unsigned u = v.u;
  u += 0x7FFF + ((u >> 16) & 1);   // round-to-nearest-even
  return (unsigned short)(u >> 16);
}

__device__ __forceinline__ void g2lds16(const unsigned short* g, unsigned short* l) {
  __builtin_amdgcn_global_load_lds(
      (const __attribute__((address_space(1))) unsigned int*)g,
      (__attribute__((address_space(3))) unsigned int*)l, 16, 0, 0);
}

// ------------- fused cast fp32 -> bf16 (x, Wq*EC, Wk, Wv) -------------
// regions are whole-block uniform: XG=4096 blocks, then 512 per weight.
__global__ __launch_bounds__(256) void cast_all_kernel(
    const float* __restrict__ x,  const float* __restrict__ Wq,
    const float* __restrict__ Wk, const float* __restrict__ Wv,
    unsigned short* __restrict__ xb,  unsigned short* __restrict__ wqb,
    unsigned short* __restrict__ wkb, unsigned short* __restrict__ wvb) {
  const int XG = (BATCH * SEQ * DIM) / 8;   // 1048576
  const int WG = (DIM * DIM) / 8;           // 131072
  int i = blockIdx.x * 256 + threadIdx.x;
  const float* in; unsigned short* out; float sc = 1.0f; int off;
  if (i < XG)               { in = x;  out = xb;  off = i; }
  else if (i < XG + WG)     { in = Wq; out = wqb; off = i - XG; sc = ECF; }
  else if (i < XG + 2 * WG) { in = Wk; out = wkb; off = i - XG - WG; }
  else                      { in = Wv; out = wvb; off = i - XG - 2 * WG; }
  const float4* p = (const float4*)in + (size_t)off * 2;
  float4 a = p[0], b = p[1];
  unsigned short r[8];
  r[0] = f2bf(a.x * sc); r[1] = f2bf(a.y * sc); r[2] = f2bf(a.z * sc); r[3] = f2bf(a.w * sc);
  r[4] = f2bf(b.x * sc); r[5] = f2bf(b.y * sc); r[6] = f2bf(b.z * sc); r[7] = f2bf(b.w * sc);
  *(uint4*)&out[(size_t)off * 8] = *(uint4*)r;
}

// ---------------- fused QKV projection GEMM --------------------------
// grid (64, 24): z = y%3 (Q/K/V, fastest -> shared A-tile in L2), n-tile = y/3.
// C[m,n] = sum_k A[m,k]*W[n,k] + bias[n]. Single-barrier double-buffered.
__global__ __launch_bounds__(256) void gemm_qkv(
    const unsigned short* __restrict__ A,
    const unsigned short* __restrict__ Wqp, const unsigned short* __restrict__ Wkp,
    const unsigned short* __restrict__ Wvp,
    const float* __restrict__ bqp, const float* __restrict__ bkp,
    const float* __restrict__ bvp,
    unsigned short* __restrict__ oq, unsigned short* __restrict__ ok,
    unsigned short* __restrict__ ov) {
  __shared__ unsigned short As[2][128 * 32];
  __shared__ unsigned short Bs[2][128 * 32];
  const int z = blockIdx.y % 3;
  const unsigned short* W = (z == 0) ? Wqp : (z == 1) ? Wkp : Wvp;
  const float* bias        = (z == 0) ? bqp : (z == 1) ? bkp : bvp;
  unsigned short* outp     = (z == 0) ? oq  : (z == 1) ? ok  : ov;
  const float bsc          = (z == 0) ? ECF : 1.0f;
  const int mode = (z == 2) ? 1 : 0;

  const int tid  = threadIdx.x;
  const int wave = tid >> 6;
  const int lane = tid & 63;
  const int lm   = lane & 15;
  const int qd   = lane >> 4;
  const int m0 = blockIdx.x * 128;
  const int n0 = (blockIdx.y / 3) * 128;
  const int wm = (wave >> 1) * 64;
  const int wn = (wave & 1) * 64;

  const f32x4 zero = {0.f, 0.f, 0.f, 0.f};
  f32x4 acc[4][4];
#pragma unroll
  for (int i = 0; i < 4; ++i)
#pragma unroll
    for (int j = 0; j < 4; ++j) acc[i][j] = zero;

  const int srow = tid >> 2;          // 0..63
  const int scol = (tid & 3) * 8;     // 0,8,16,24

  // prologue stage for kt=0 into buf 0
  g2lds16(&A[(size_t)(m0 + srow) * DIM + scol],      &As[0][(size_t)tid * 8]);
  g2lds16(&A[(size_t)(m0 + 64 + srow) * DIM + scol], &As[0][2048 + (size_t)tid * 8]);
  g2lds16(&W[(size_t)(n0 + srow) * DIM + scol],      &Bs[0][(size_t)tid * 8]);
  g2lds16(&W[(size_t)(n0 + 64 + srow) * DIM + scol], &Bs[0][2048 + (size_t)tid * 8]);

  for (int it = 0; it < DIM / 32; ++it) {
    const int cur = it & 1;
    __syncthreads();   // drains per-wave vmcnt -> buf[cur] valid; prev reads done
    if (it + 1 < DIM / 32) {
      const int kt = (it + 1) * 32;
      const int nb = cur ^ 1;
      g2lds16(&A[(size_t)(m0 + srow) * DIM + kt + scol],      &As[nb][(size_t)tid * 8]);
      g2lds16(&A[(size_t)(m0 + 64 + srow) * DIM + kt + scol], &As[nb][2048 + (size_t)tid * 8]);
      g2lds16(&W[(size_t)(n0 + srow) * DIM + kt + scol],      &Bs[nb][(size_t)tid * 8]);
      g2lds16(&W[(size_t)(n0 + 64 + srow) * DIM + kt + scol], &Bs[nb][2048 + (size_t)tid * 8]);
    }

    bf16x8 af[4], bfr[4];
#pragma unroll
    for (int i = 0; i < 4; ++i) af[i]  = *(const bf16x8*)&As[cur][(wm + i * 16 + lm) * 32 + qd * 8];
#pragma unroll
    for (int j = 0; j < 4; ++j) bfr[j] = *(const bf16x8*)&Bs[cur][(wn + j * 16 + lm) * 32 + qd * 8];
#pragma unroll
    for (int i = 0; i < 4; ++i)
#pragma unroll
      for (int j = 0; j < 4; ++j)
        acc[i][j] = __builtin_amdgcn_mfma_f32_16x16x32_bf16(af[i], bfr[j], acc[i][j], 0, 0, 0);
  }

  // epilogue: +bias (scaled for Q), cast bf16, permuted store
#pragma unroll
  for (int j = 0; j < 4; ++j) {
    int col = n0 + wn + j * 16 + lm;       // n index
    float bb = bias[col] * bsc;
    int h = col >> 6, hd = col & 63;
#pragma unroll
    for (int i = 0; i < 4; ++i) {
#pragma unroll
      for (int r = 0; r < 4; ++r) {
        int row = m0 + wm + i * 16 + qd * 4 + r;   // m index
        int b = row >> 11, s = row & 2047;
        float v = acc[i][j][r] + bb;
        size_t idx;
        if (mode == 0) idx = ((size_t)(b * NH + h) * SEQ + s) * HD + hd;
        else           idx = ((size_t)(b * NH + h) * HD + hd) * SEQ + s;
        outp[idx] = f2bf(v);
      }
    }
  }
}

// ---------------- flash attention (no-max softmax, S^T trick) --------
// Q (pre-scaled by EC),K: [bh, s, hd] bf16.  V: [bh, hd, s] bf16.
// out: [b, s, h*hd] fp32.  128 q-rows/block; single-barrier dbuf K/V staging.
#define LDP 72
__global__ __launch_bounds__(256, 3) void flash_kernel(
    const unsigned short* __restrict__ Qw, const unsigned short* __restrict__ Kw,
    const unsigned short* __restrict__ Vw, float* __restrict__ out) {
  __shared__ unsigned short Ks2[2][2 * 64 * 32];   // [buf][hd_half][key][32]
  __shared__ unsigned short Vs2[2][2 * 64 * 32];   // [buf][key_half][hd][32]
  __shared__ unsigned short Ps[128 * LDP];         // [qrow][key]
  __shared__ float Ls[128];

  const int tid  = threadIdx.x;
  const int w    = tid >> 6;
  const int lane = tid & 63;
  const int lm   = lane & 15;
  const int qd   = lane >> 4;
  const int bh   = blockIdx.y;
  const int q0   = blockIdx.x * 128;

  const unsigned short* Qbase = Qw + (size_t)bh * (SEQ * HD);
  const unsigned short* Kbase = Kw + (size_t)bh * (SEQ * HD);
  const unsigned short* Vbase = Vw + (size_t)bh * (HD * SEQ);

  // Q fragments in registers (already scaled by log2(e)/8)
  bf16x8 qf[2][2];
#pragma unroll
  for (int g = 0; g < 2; ++g)
#pragma unroll
    for (int h = 0; h < 2; ++h)
      qf[g][h] = *(const bf16x8*)&Qbase[(size_t)(q0 + w * 32 + g * 16 + lm) * HD + h * 32 + qd * 8];

  const f32x4 zero = {0.f, 0.f, 0.f, 0.f};
  f32x4 o[2][4];
#pragma unroll
  for (int g = 0; g < 2; ++g)
#pragma unroll
    for (int jn = 0; jn < 4; ++jn) o[g][jn] = zero;
  float psg[2] = {0.f, 0.f};

  const int srow = tid >> 2;          // 0..63
  const int scol = (tid & 3) * 8;     // 0,8,16,24

  // prologue stage kt=0 into buf 0
  g2lds16(&Kbase[(size_t)srow * HD + scol],      &Ks2[0][(size_t)tid * 8]);
  g2lds16(&Kbase[(size_t)srow * HD + 32 + scol], &Ks2[0][2048 + (size_t)tid * 8]);
  g2lds16(&Vbase[(size_t)srow * SEQ + scol],      &Vs2[0][(size_t)tid * 8]);
  g2lds16(&Vbase[(size_t)srow * SEQ + 32 + scol], &Vs2[0][2048 + (size_t)tid * 8]);

  for (int kt = 0; kt < SEQ / 64; ++kt) {
    const int cur = kt & 1;
    __syncthreads();   // per-wave vmcnt drain -> buf[cur] complete; prev reads done
    if (kt + 1 < SEQ / 64) {
      const int nb = cur ^ 1;
      const int k1 = (kt + 1) * 64;
      g2lds16(&Kbase[(size_t)(k1 + srow) * HD + scol],       &Ks2[nb][(size_t)tid * 8]);
      g2lds16(&Kbase[(size_t)(k1 + srow) * HD + 32 + scol],  &Ks2[nb][2048 + (size_t)tid * 8]);
      g2lds16(&Vbase[(size_t)srow * SEQ + k1 + scol],        &Vs2[nb][(size_t)tid * 8]);
      g2lds16(&Vbase[(size_t)srow * SEQ + k1 + 32 + scol],   &Vs2[nb][2048 + (size_t)tid * 8]);
    }

    // S^T = K Q^T : rows key=jk*16+qd*4+r, cols qrow=g*16+lm
#pragma unroll
    for (int jk = 0; jk < 4; ++jk) {
      bf16x8 kf0 = *(const bf16x8*)&Ks2[cur][(jk * 16 + lm) * 32 + qd * 8];
      bf16x8 kf1 = *(const bf16x8*)&Ks2[cur][2048 + (jk * 16 + lm) * 32 + qd * 8];
      f32x4 st[2];
#pragma unroll
      for (int g = 0; g < 2; ++g) {
        st[g] = __builtin_amdgcn_mfma_f32_16x16x32_bf16(kf0, qf[g][0], zero, 0, 0, 0);
        st[g] = __builtin_amdgcn_mfma_f32_16x16x32_bf16(kf1, qf[g][1], st[g], 0, 0, 0);
      }
      // p = exp2(s) (scale pre-folded into Q); pack bf16, one b64 write per g
#pragma unroll
      for (int g = 0; g < 2; ++g) {
        float p0 = __builtin_amdgcn_exp2f(st[g][0]);
        float p1 = __builtin_amdgcn_exp2f(st[g][1]);
        float p2 = __builtin_amdgcn_exp2f(st[g][2]);
        float p3 = __builtin_amdgcn_exp2f(st[g][3]);
        psg[g] += (p0 + p1) + (p2 + p3);
        uint2 pk;
        pk.x = __builtin_amdgcn_perm(__float_as_uint(p1), __float_as_uint(p0), 0x07060302);
        pk.y = __builtin_amdgcn_perm(__float_as_uint(p3), __float_as_uint(p2), 0x07060302);
        *(uint2*)&Ps[(w * 32 + g * 16 + lm) * LDP + jk * 16 + qd * 4] = pk;
      }
    }

    // same-wave LDS RAW (wave w only touches its own 32 Ps rows)
    asm volatile("s_waitcnt lgkmcnt(0)" ::: "memory");

    // O += P V
#pragma unroll
    for (int h2 = 0; h2 < 2; ++h2) {
      bf16x8 pf0 = *(const bf16x8*)&Ps[(w * 32 + lm) * LDP + h2 * 32 + qd * 8];
      bf16x8 pf1 = *(const bf16x8*)&Ps[(w * 32 + 16 + lm) * LDP + h2 * 32 + qd * 8];
#pragma unroll
      for (int jn = 0; jn < 4; ++jn) {
        bf16x8 vf = *(const bf16x8*)&Vs2[cur][h2 * 2048 + (jn * 16 + lm) * 32 + qd * 8];
        o[0][jn] = __builtin_amdgcn_mfma_f32_16x16x32_bf16(pf0, vf, o[0][jn], 0, 0, 0);
        o[1][jn] = __builtin_amdgcn_mfma_f32_16x16x32_bf16(pf1, vf, o[1][jn], 0, 0, 0);
      }
    }
  }

  // final row-sum reduce (over the 4 qd lane-groups) and normalize
  float l0 = psg[0], l1 = psg[1];
  l0 += __shfl_xor(l0, 16); l0 += __shfl_xor(l0, 32);
  l1 += __shfl_xor(l1, 16); l1 += __shfl_xor(l1, 32);
  if (qd == 0) {
    Ls[w * 32 + lm]      = l0;
    Ls[w * 32 + 16 + lm] = l1;
  }
  asm volatile("s_waitcnt lgkmcnt(0)" ::: "memory");

  const int b = bh >> 4, hh = bh & 15;
#pragma unroll
  for (int g = 0; g < 2; ++g)
#pragma unroll
    for (int r = 0; r < 4; ++r) {
      float inv = 1.0f / Ls[w * 32 + g * 16 + qd * 4 + r];
      int qrow = q0 + w * 32 + g * 16 + qd * 4 + r;
#pragma unroll
      for (int jn = 0; jn < 4; ++jn)
        out[(size_t)(b * SEQ + qrow) * DIM + hh * HD + jn * 16 + lm] = o[g][jn][r] * inv;
    }
}

extern "C" void kernel_launch(void* const* d_in, const int* in_sizes, int n_in,
                              void* d_out, int out_size, void* d_ws, size_t ws_size,
                              hipStream_t stream) {
  const float* x  = (const float*)d_in[0];
  const float* Wq = (const float*)d_in[1];
  const float* bq = (const float*)d_in[2];
  const float* Wk = (const float*)d_in[3];
  const float* bk = (const float*)d_in[4];
  const float* Wv = (const float*)d_in[5];
  const float* bv = (const float*)d_in[6];
  float* out = (float*)d_out;

  unsigned short* ws = (unsigned short*)d_ws;
  const size_t XE = (size_t)BATCH * SEQ * DIM;   // 8388608
  const size_t WE = (size_t)DIM * DIM;           // 1048576
  unsigned short* xb  = ws;
  unsigned short* wqb = xb + XE;
  unsigned short* wkb = wqb + WE;
  unsigned short* wvb = wkb + WE;
  unsigned short* qb  = wvb + WE;
  unsigned short* kb  = qb + XE;
  unsigned short* vb  = kb + XE;

  const int total_groups = (int)(XE / 8 + 3 * (WE / 8));   // 1441792
  cast_all_kernel<<<total_groups / 256, 256, 0, stream>>>(
      x, Wq, Wk, Wv, xb, wqb, wkb, wvb);

  dim3 gg(64, 24);
  gemm_qkv<<<gg, 256, 0, stream>>>(xb, wqb, wkb, wvb, bq, bk, bv, qb, kb, vb);

  dim3 fg(SEQ / 128, BATCH * NH);
  flash_kernel<<<fg, 256, 0, stream>>>(qb, kb, vb, out);
}

// Round 4
// 256.211 us; speedup vs baseline: 1.1310x; 1.1310x over previous
//
#include <hip/hip_runtime.h>

typedef __bf16 bf16x8 __attribute__((ext_vector_type(8)));
typedef float f32x4 __attribute__((ext_vector_type(4)));

#define BATCH 4
#define SEQ   2048
#define DIM   1024
#define NH    16
#define HD    64
#define ECF   0.18033688f   // log2(e)/8 : folds 1/sqrt(64) into exp2

__device__ __forceinline__ unsigned short f2bf(float f) {
  union { float f; unsigned u; } v; v.f = f;
  unsigned u = v.u;
  u += 0x7FFF + ((u >> 16) & 1);   // round-to-nearest-even
  return (unsigned short)(u >> 16);
}

__device__ __forceinline__ void g2lds16(const unsigned short* g, unsigned short* l) {
  __builtin_amdgcn_global_load_lds(
      (const __attribute__((address_space(1))) unsigned int*)g,
      (__attribute__((address_space(3))) unsigned int*)l, 16, 0, 0);
}

// ------------- fused cast fp32 -> bf16 (x, Wq*EC, Wk, Wv) -------------
__global__ __launch_bounds__(256) void cast_all_kernel(
    const float* __restrict__ x,  const float* __restrict__ Wq,
    const float* __restrict__ Wk, const float* __restrict__ Wv,
    unsigned short* __restrict__ xb,  unsigned short* __restrict__ wqb,
    unsigned short* __restrict__ wkb, unsigned short* __restrict__ wvb) {
  const int XG = (BATCH * SEQ * DIM) / 8;   // 1048576
  const int WG = (DIM * DIM) / 8;           // 131072
  int i = blockIdx.x * 256 + threadIdx.x;
  const float* in; unsigned short* out; float sc = 1.0f; int off;
  if (i < XG)               { in = x;  out = xb;  off = i; }
  else if (i < XG + WG)     { in = Wq; out = wqb; off = i - XG; sc = ECF; }
  else if (i < XG + 2 * WG) { in = Wk; out = wkb; off = i - XG - WG; }
  else                      { in = Wv; out = wvb; off = i - XG - 2 * WG; }
  const float4* p = (const float4*)in + (size_t)off * 2;
  float4 a = p[0], b = p[1];
  unsigned short r[8];
  r[0] = f2bf(a.x * sc); r[1] = f2bf(a.y * sc); r[2] = f2bf(a.z * sc); r[3] = f2bf(a.w * sc);
  r[4] = f2bf(b.x * sc); r[5] = f2bf(b.y * sc); r[6] = f2bf(b.z * sc); r[7] = f2bf(b.w * sc);
  *(uint4*)&out[(size_t)off * 8] = *(uint4*)r;
}

// ---------------- fused QKV projection GEMM --------------------------
// grid (64, 8, 3): z selects Q/K/V. Single-buffer, 2-barrier (R2 structure:
// 4+ blocks/CU inter-block overlap beats explicit dbuf — R3 post-mortem).
// C[m,n] = sum_k A[m,k]*W[n,k] + bias[n].
__global__ __launch_bounds__(256) void gemm_qkv(
    const unsigned short* __restrict__ A,
    const unsigned short* __restrict__ Wqp, const unsigned short* __restrict__ Wkp,
    const unsigned short* __restrict__ Wvp,
    const float* __restrict__ bqp, const float* __restrict__ bkp,
    const float* __restrict__ bvp,
    unsigned short* __restrict__ oq, unsigned short* __restrict__ ok,
    unsigned short* __restrict__ ov) {
  __shared__ unsigned short As[128 * 32];
  __shared__ unsigned short Bs[128 * 32];
  const int z = blockIdx.z;
  const unsigned short* W = (z == 0) ? Wqp : (z == 1) ? Wkp : Wvp;
  const float* bias        = (z == 0) ? bqp : (z == 1) ? bkp : bvp;
  unsigned short* outp     = (z == 0) ? oq  : (z == 1) ? ok  : ov;
  const float bsc          = (z == 0) ? ECF : 1.0f;   // bq scaled like Wq
  const int mode = (z == 2) ? 1 : 0;

  const int tid  = threadIdx.x;
  const int wave = tid >> 6;
  const int lane = tid & 63;
  const int lm   = lane & 15;
  const int qd   = lane >> 4;
  const int m0 = blockIdx.x * 128;
  const int n0 = blockIdx.y * 128;
  const int wm = (wave >> 1) * 64;
  const int wn = (wave & 1) * 64;

  const f32x4 zero = {0.f, 0.f, 0.f, 0.f};
  f32x4 acc[4][4];
#pragma unroll
  for (int i = 0; i < 4; ++i)
#pragma unroll
    for (int j = 0; j < 4; ++j) acc[i][j] = zero;

  const int srow = tid >> 2;          // 0..63
  const int scol = (tid & 3) * 8;     // 0,8,16,24

  for (int kt = 0; kt < DIM; kt += 32) {
    __syncthreads();
    g2lds16(&A[(size_t)(m0 + srow) * DIM + kt + scol],       &As[(size_t)tid * 8]);
    g2lds16(&A[(size_t)(m0 + 64 + srow) * DIM + kt + scol],  &As[2048 + (size_t)tid * 8]);
    g2lds16(&W[(size_t)(n0 + srow) * DIM + kt + scol],       &Bs[(size_t)tid * 8]);
    g2lds16(&W[(size_t)(n0 + 64 + srow) * DIM + kt + scol],  &Bs[2048 + (size_t)tid * 8]);
    __syncthreads();

    bf16x8 af[4], bfr[4];
#pragma unroll
    for (int i = 0; i < 4; ++i) af[i]  = *(const bf16x8*)&As[(wm + i * 16 + lm) * 32 + qd * 8];
#pragma unroll
    for (int j = 0; j < 4; ++j) bfr[j] = *(const bf16x8*)&Bs[(wn + j * 16 + lm) * 32 + qd * 8];
#pragma unroll
    for (int i = 0; i < 4; ++i)
#pragma unroll
      for (int j = 0; j < 4; ++j)
        acc[i][j] = __builtin_amdgcn_mfma_f32_16x16x32_bf16(af[i], bfr[j], acc[i][j], 0, 0, 0);
  }

  // epilogue: +bias, cast bf16, permuted store
#pragma unroll
  for (int j = 0; j < 4; ++j) {
    int col = n0 + wn + j * 16 + lm;       // n index
    float bb = bias[col] * bsc;
    int h = col >> 6, hd = col & 63;
#pragma unroll
    for (int i = 0; i < 4; ++i) {
      int rowb = m0 + wm + i * 16 + qd * 4;   // base m index (r=0)
      int b = rowb >> 11, s = rowb & 2047;
      if (mode == 0) {
        // Q/K: [b,h,s,hd] — 2B stores, lane-coalesced over hd
#pragma unroll
        for (int r = 0; r < 4; ++r) {
          float v = acc[i][j][r] + bb;
          outp[((size_t)(b * NH + h) * SEQ + (s + r)) * HD + hd] = f2bf(v);
        }
      } else {
        // V^T: [b,h,hd,s] — r maps to consecutive s: pack one 8B store
        unsigned short pk[4];
#pragma unroll
        for (int r = 0; r < 4; ++r) pk[r] = f2bf(acc[i][j][r] + bb);
        size_t idx = ((size_t)(b * NH + h) * HD + hd) * SEQ + s;
        *(uint2*)&outp[idx] = *(uint2*)pk;
      }
    }
  }
}

// ---------------- flash attention (no-max softmax, S^T trick) --------
// Q (pre-scaled by EC),K: [bh, s, hd] bf16.  V: [bh, hd, s] bf16.
// out: [b, s, h*hd] fp32.  128 q-rows/block; R2 single-buffer structure.
#define LDP 72
__global__ __launch_bounds__(256, 4) void flash_kernel(
    const unsigned short* __restrict__ Qw, const unsigned short* __restrict__ Kw,
    const unsigned short* __restrict__ Vw, float* __restrict__ out) {
  __shared__ unsigned short Ks2[2 * 64 * 32];   // [hd_half][key][32]
  __shared__ unsigned short Vs2[2 * 64 * 32];   // [key_half][hd][32]
  __shared__ unsigned short Ps[128 * LDP];      // [qrow][key]
  __shared__ float Ls[128];

  const int tid  = threadIdx.x;
  const int w    = tid >> 6;
  const int lane = tid & 63;
  const int lm   = lane & 15;
  const int qd   = lane >> 4;
  const int bh   = blockIdx.y;
  const int q0   = blockIdx.x * 128;

  const unsigned short* Qbase = Qw + (size_t)bh * (SEQ * HD);
  const unsigned short* Kbase = Kw + (size_t)bh * (SEQ * HD);
  const unsigned short* Vbase = Vw + (size_t)bh * (HD * SEQ);

  // Q fragments in registers (already scaled by log2(e)/8)
  bf16x8 qf[2][2];
#pragma unroll
  for (int g = 0; g < 2; ++g)
#pragma unroll
    for (int h = 0; h < 2; ++h)
      qf[g][h] = *(const bf16x8*)&Qbase[(size_t)(q0 + w * 32 + g * 16 + lm) * HD + h * 32 + qd * 8];

  const f32x4 zero = {0.f, 0.f, 0.f, 0.f};
  f32x4 o[2][4];
#pragma unroll
  for (int g = 0; g < 2; ++g)
#pragma unroll
    for (int jn = 0; jn < 4; ++jn) o[g][jn] = zero;
  float psg[2] = {0.f, 0.f};

  const int srow = tid >> 2;          // 0..63
  const int scol = (tid & 3) * 8;     // 0,8,16,24

  for (int kt = 0; kt < SEQ / 64; ++kt) {
    __syncthreads();
    g2lds16(&Kbase[(size_t)(kt * 64 + srow) * HD + scol],      &Ks2[(size_t)tid * 8]);
    g2lds16(&Kbase[(size_t)(kt * 64 + srow) * HD + 32 + scol], &Ks2[2048 + (size_t)tid * 8]);
    g2lds16(&Vbase[(size_t)srow * SEQ + kt * 64 + scol],       &Vs2[(size_t)tid * 8]);
    g2lds16(&Vbase[(size_t)srow * SEQ + kt * 64 + 32 + scol],  &Vs2[2048 + (size_t)tid * 8]);
    __syncthreads();

    // S^T = K Q^T : rows key=jk*16+qd*4+r, cols qrow=g*16+lm
#pragma unroll
    for (int jk = 0; jk < 4; ++jk) {
      bf16x8 kf0 = *(const bf16x8*)&Ks2[(jk * 16 + lm) * 32 + qd * 8];
      bf16x8 kf1 = *(const bf16x8*)&Ks2[2048 + (jk * 16 + lm) * 32 + qd * 8];
      f32x4 st[2];
#pragma unroll
      for (int g = 0; g < 2; ++g) {
        st[g] = __builtin_amdgcn_mfma_f32_16x16x32_bf16(kf0, qf[g][0], zero, 0, 0, 0);
        st[g] = __builtin_amdgcn_mfma_f32_16x16x32_bf16(kf1, qf[g][1], st[g], 0, 0, 0);
      }
      // p = exp2(s) (scale pre-folded into Q); pack bf16, one b64 write per g
#pragma unroll
      for (int g = 0; g < 2; ++g) {
        float p0 = __builtin_amdgcn_exp2f(st[g][0]);
        float p1 = __builtin_amdgcn_exp2f(st[g][1]);
        float p2 = __builtin_amdgcn_exp2f(st[g][2]);
        float p3 = __builtin_amdgcn_exp2f(st[g][3]);
        psg[g] += (p0 + p1) + (p2 + p3);
        uint2 pk;
        pk.x = __builtin_amdgcn_perm(__float_as_uint(p1), __float_as_uint(p0), 0x07060302);
        pk.y = __builtin_amdgcn_perm(__float_as_uint(p3), __float_as_uint(p2), 0x07060302);
        *(uint2*)&Ps[(w * 32 + g * 16 + lm) * LDP + jk * 16 + qd * 4] = pk;
      }
    }

    // same-wave LDS RAW (wave w only touches its own 32 Ps rows)
    asm volatile("s_waitcnt lgkmcnt(0)" ::: "memory");

    // O += P V
#pragma unroll
    for (int h2 = 0; h2 < 2; ++h2) {
      bf16x8 pf0 = *(const bf16x8*)&Ps[(w * 32 + lm) * LDP + h2 * 32 + qd * 8];
      bf16x8 pf1 = *(const bf16x8*)&Ps[(w * 32 + 16 + lm) * LDP + h2 * 32 + qd * 8];
#pragma unroll
      for (int jn = 0; jn < 4; ++jn) {
        bf16x8 vf = *(const bf16x8*)&Vs2[h2 * 2048 + (jn * 16 + lm) * 32 + qd * 8];
        o[0][jn] = __builtin_amdgcn_mfma_f32_16x16x32_bf16(pf0, vf, o[0][jn], 0, 0, 0);
        o[1][jn] = __builtin_amdgcn_mfma_f32_16x16x32_bf16(pf1, vf, o[1][jn], 0, 0, 0);
      }
    }
  }

  // final row-sum reduce (over the 4 qd lane-groups) and normalize
  float l0 = psg[0], l1 = psg[1];
  l0 += __shfl_xor(l0, 16); l0 += __shfl_xor(l0, 32);
  l1 += __shfl_xor(l1, 16); l1 += __shfl_xor(l1, 32);
  if (qd == 0) {
    Ls[w * 32 + lm]      = l0;
    Ls[w * 32 + 16 + lm] = l1;
  }
  asm volatile("s_waitcnt lgkmcnt(0)" ::: "memory");

  const int b = bh >> 4, hh = bh & 15;
#pragma unroll
  for (int g = 0; g < 2; ++g)
#pragma unroll
    for (int r = 0; r < 4; ++r) {
      float inv = 1.0f / Ls[w * 32 + g * 16 + qd * 4 + r];
      int qrow = q0 + w * 32 + g * 16 + qd * 4 + r;
#pragma unroll
      for (int jn = 0; jn < 4; ++jn)
        out[(size_t)(b * SEQ + qrow) * DIM + hh * HD + jn * 16 + lm] = o[g][jn][r] * inv;
    }
}

extern "C" void kernel_launch(void* const* d_in, const int* in_sizes, int n_in,
                              void* d_out, int out_size, void* d_ws, size_t ws_size,
                              hipStream_t stream) {
  const float* x  = (const float*)d_in[0];
  const float* Wq = (const float*)d_in[1];
  const float* bq = (const float*)d_in[2];
  const float* Wk = (const float*)d_in[3];
  const float* bk = (const float*)d_in[4];
  const float* Wv = (const float*)d_in[5];
  const float* bv = (const float*)d_in[6];
  float* out = (float*)d_out;

  unsigned short* ws = (unsigned short*)d_ws;
  const size_t XE = (size_t)BATCH * SEQ * DIM;   // 8388608
  const size_t WE = (size_t)DIM * DIM;           // 1048576
  unsigned short* xb  = ws;
  unsigned short* wqb = xb + XE;
  unsigned short* wkb = wqb + WE;
  unsigned short* wvb = wkb + WE;
  unsigned short* qb  = wvb + WE;
  unsigned short* kb  = qb + XE;
  unsigned short* vb  = kb + XE;

  const int total_groups = (int)(XE / 8 + 3 * (WE / 8));   // 1441792
  cast_all_kernel<<<total_groups / 256, 256, 0, stream>>>(
      x, Wq, Wk, Wv, xb, wqb, wkb, wvb);

  dim3 gg(64, 8, 3);
  gemm_qkv<<<gg, 256, 0, stream>>>(xb, wqb, wkb, wvb, bq, bk, bv, qb, kb, vb);

  dim3 fg(SEQ / 128, BATCH * NH);
  flash_kernel<<<fg, 256, 0, stream>>>(qb, kb, vb, out);
}

// Round 5
// 248.104 us; speedup vs baseline: 1.1680x; 1.0327x over previous
//
#include <hip/hip_runtime.h>

typedef __bf16 bf16x8 __attribute__((ext_vector_type(8)));
typedef float f32x4 __attribute__((ext_vector_type(4)));

#define BATCH 4
#define SEQ   2048
#define DIM   1024
#define NH    16
#define HD    64
#define ECF   0.18033688f   // log2(e)/8 : folds 1/sqrt(64) into exp2

__device__ __forceinline__ unsigned short f2bf(float f) {
  union { float f; unsigned u; } v; v.f = f;
  unsigned u = v.u;
  u += 0x7FFF + ((u >> 16) & 1);   // round-to-nearest-even
  return (unsigned short)(u >> 16);
}

__device__ __forceinline__ void g2lds16(const unsigned short* g, unsigned short* l) {
  __builtin_amdgcn_global_load_lds(
      (const __attribute__((address_space(1))) unsigned int*)g,
      (__attribute__((address_space(3))) unsigned int*)l, 16, 0, 0);
}

// ------------- fused cast fp32 -> bf16 (x, Wq*EC, Wk, Wv) -------------
__global__ __launch_bounds__(256) void cast_all_kernel(
    const float* __restrict__ x,  const float* __restrict__ Wq,
    const float* __restrict__ Wk, const float* __restrict__ Wv,
    unsigned short* __restrict__ xb,  unsigned short* __restrict__ wqb,
    unsigned short* __restrict__ wkb, unsigned short* __restrict__ wvb) {
  const int XG = (BATCH * SEQ * DIM) / 8;   // 1048576
  const int WG = (DIM * DIM) / 8;           // 131072
  int i = blockIdx.x * 256 + threadIdx.x;
  const float* in; unsigned short* out; float sc = 1.0f; int off;
  if (i < XG)               { in = x;  out = xb;  off = i; }
  else if (i < XG + WG)     { in = Wq; out = wqb; off = i - XG; sc = ECF; }
  else if (i < XG + 2 * WG) { in = Wk; out = wkb; off = i - XG - WG; }
  else                      { in = Wv; out = wvb; off = i - XG - 2 * WG; }
  const float4* p = (const float4*)in + (size_t)off * 2;
  float4 a = p[0], b = p[1];
  unsigned short r[8];
  r[0] = f2bf(a.x * sc); r[1] = f2bf(a.y * sc); r[2] = f2bf(a.z * sc); r[3] = f2bf(a.w * sc);
  r[4] = f2bf(b.x * sc); r[5] = f2bf(b.y * sc); r[6] = f2bf(b.z * sc); r[7] = f2bf(b.w * sc);
  *(uint4*)&out[(size_t)off * 8] = *(uint4*)r;
}

// ---------------- fused QKV projection GEMM --------------------------
// grid (64, 8, 3): z selects Q/K/V. Single-buffer, 2-barrier (R3 post-mortem:
// occupancy > explicit dbuf). LDS rows XOR-chunk-swizzled: row R's logical
// 16B chunk c lives at position c ^ ((R>>1)&3)  -> 2-way banks (free, m136)
// instead of 8-way at the naive 64B row stride.
__global__ __launch_bounds__(256) void gemm_qkv(
    const unsigned short* __restrict__ A,
    const unsigned short* __restrict__ Wqp, const unsigned short* __restrict__ Wkp,
    const unsigned short* __restrict__ Wvp,
    const float* __restrict__ bqp, const float* __restrict__ bkp,
    const float* __restrict__ bvp,
    unsigned short* __restrict__ oq, unsigned short* __restrict__ ok,
    unsigned short* __restrict__ ov) {
  __shared__ unsigned short As[128 * 32];
  __shared__ unsigned short Bs[128 * 32];
  const int z = blockIdx.z;
  const unsigned short* W = (z == 0) ? Wqp : (z == 1) ? Wkp : Wvp;
  const float* bias        = (z == 0) ? bqp : (z == 1) ? bkp : bvp;
  unsigned short* outp     = (z == 0) ? oq  : (z == 1) ? ok  : ov;
  const float bsc          = (z == 0) ? ECF : 1.0f;   // bq scaled like Wq
  const int mode = (z == 2) ? 1 : 0;

  const int tid  = threadIdx.x;
  const int wave = tid >> 6;
  const int lane = tid & 63;
  const int lm   = lane & 15;
  const int qd   = lane >> 4;
  const int m0 = blockIdx.x * 128;
  const int n0 = blockIdx.y * 128;
  const int wm = (wave >> 1) * 64;
  const int wn = (wave & 1) * 64;

  const f32x4 zero = {0.f, 0.f, 0.f, 0.f};
  f32x4 acc[4][4];
#pragma unroll
  for (int i = 0; i < 4; ++i)
#pragma unroll
    for (int j = 0; j < 4; ++j) acc[i][j] = zero;

  const int srow = tid >> 2;                               // 0..63
  const int scol = (((tid & 3) ^ ((tid >> 3) & 3))) * 8;   // swizzled source chunk
  const int cs   = (qd ^ ((lm >> 1) & 3)) * 8;             // swizzled read chunk

  for (int kt = 0; kt < DIM; kt += 32) {
    __syncthreads();
    g2lds16(&A[(size_t)(m0 + srow) * DIM + kt + scol],       &As[(size_t)tid * 8]);
    g2lds16(&A[(size_t)(m0 + 64 + srow) * DIM + kt + scol],  &As[2048 + (size_t)tid * 8]);
    g2lds16(&W[(size_t)(n0 + srow) * DIM + kt + scol],       &Bs[(size_t)tid * 8]);
    g2lds16(&W[(size_t)(n0 + 64 + srow) * DIM + kt + scol],  &Bs[2048 + (size_t)tid * 8]);
    __syncthreads();

    bf16x8 af[4], bfr[4];
#pragma unroll
    for (int i = 0; i < 4; ++i) af[i]  = *(const bf16x8*)&As[(wm + i * 16 + lm) * 32 + cs];
#pragma unroll
    for (int j = 0; j < 4; ++j) bfr[j] = *(const bf16x8*)&Bs[(wn + j * 16 + lm) * 32 + cs];
#pragma unroll
    for (int i = 0; i < 4; ++i)
#pragma unroll
      for (int j = 0; j < 4; ++j)
        acc[i][j] = __builtin_amdgcn_mfma_f32_16x16x32_bf16(af[i], bfr[j], acc[i][j], 0, 0, 0);
  }

  // epilogue: +bias, cast bf16, permuted store
#pragma unroll
  for (int j = 0; j < 4; ++j) {
    int col = n0 + wn + j * 16 + lm;       // n index
    float bb = bias[col] * bsc;
    int h = col >> 6, hd = col & 63;
#pragma unroll
    for (int i = 0; i < 4; ++i) {
      int rowb = m0 + wm + i * 16 + qd * 4;   // base m index (r=0)
      int b = rowb >> 11, s = rowb & 2047;
      if (mode == 0) {
        // Q/K: [b,h,s,hd] — 2B stores, lane-coalesced over hd
#pragma unroll
        for (int r = 0; r < 4; ++r) {
          float v = acc[i][j][r] + bb;
          outp[((size_t)(b * NH + h) * SEQ + (s + r)) * HD + hd] = f2bf(v);
        }
      } else {
        // V^T: [b,h,hd,s] — r maps to consecutive s: pack one 8B store
        unsigned short pk[4];
#pragma unroll
        for (int r = 0; r < 4; ++r) pk[r] = f2bf(acc[i][j][r] + bb);
        size_t idx = ((size_t)(b * NH + h) * HD + hd) * SEQ + s;
        *(uint2*)&outp[idx] = *(uint2*)pk;
      }
    }
  }
}

// ---------------- flash attention (no-max softmax, S^T trick) --------
// Q (pre-scaled by EC),K: [bh, s, hd] bf16.  V: [bh, hd, s] bf16.
// out: [b, s, h*hd] fp32.  128 q-rows/block; K/V tiles XOR-chunk-swizzled.
#define LDP 72
__global__ __launch_bounds__(256, 4) void flash_kernel(
    const unsigned short* __restrict__ Qw, const unsigned short* __restrict__ Kw,
    const unsigned short* __restrict__ Vw, float* __restrict__ out) {
  __shared__ unsigned short Ks2[2 * 64 * 32];   // [hd_half][key][32] swizzled
  __shared__ unsigned short Vs2[2 * 64 * 32];   // [key_half][hd][32] swizzled
  __shared__ unsigned short Ps[128 * LDP];      // [qrow][key]
  __shared__ float Ls[128];

  const int tid  = threadIdx.x;
  const int w    = tid >> 6;
  const int lane = tid & 63;
  const int lm   = lane & 15;
  const int qd   = lane >> 4;
  const int bh   = blockIdx.y;
  const int q0   = blockIdx.x * 128;

  const unsigned short* Qbase = Qw + (size_t)bh * (SEQ * HD);
  const unsigned short* Kbase = Kw + (size_t)bh * (SEQ * HD);
  const unsigned short* Vbase = Vw + (size_t)bh * (HD * SEQ);

  // Q fragments in registers (already scaled by log2(e)/8)
  bf16x8 qf[2][2];
#pragma unroll
  for (int g = 0; g < 2; ++g)
#pragma unroll
    for (int h = 0; h < 2; ++h)
      qf[g][h] = *(const bf16x8*)&Qbase[(size_t)(q0 + w * 32 + g * 16 + lm) * HD + h * 32 + qd * 8];

  const f32x4 zero = {0.f, 0.f, 0.f, 0.f};
  f32x4 o[2][4];
#pragma unroll
  for (int g = 0; g < 2; ++g)
#pragma unroll
    for (int jn = 0; jn < 4; ++jn) o[g][jn] = zero;
  float psg[2] = {0.f, 0.f};

  const int srow = tid >> 2;                               // 0..63
  const int scol = (((tid & 3) ^ ((tid >> 3) & 3))) * 8;   // swizzled source chunk
  const int cs   = (qd ^ ((lm >> 1) & 3)) * 8;             // swizzled read chunk

  for (int kt = 0; kt < SEQ / 64; ++kt) {
    __syncthreads();
    g2lds16(&Kbase[(size_t)(kt * 64 + srow) * HD + scol],      &Ks2[(size_t)tid * 8]);
    g2lds16(&Kbase[(size_t)(kt * 64 + srow) * HD + 32 + scol], &Ks2[2048 + (size_t)tid * 8]);
    g2lds16(&Vbase[(size_t)srow * SEQ + kt * 64 + scol],       &Vs2[(size_t)tid * 8]);
    g2lds16(&Vbase[(size_t)srow * SEQ + kt * 64 + 32 + scol],  &Vs2[2048 + (size_t)tid * 8]);
    __syncthreads();

    // S^T = K Q^T : rows key=jk*16+qd*4+r, cols qrow=g*16+lm
#pragma unroll
    for (int jk = 0; jk < 4; ++jk) {
      bf16x8 kf0 = *(const bf16x8*)&Ks2[(jk * 16 + lm) * 32 + cs];
      bf16x8 kf1 = *(const bf16x8*)&Ks2[2048 + (jk * 16 + lm) * 32 + cs];
      f32x4 st[2];
#pragma unroll
      for (int g = 0; g < 2; ++g) {
        st[g] = __builtin_amdgcn_mfma_f32_16x16x32_bf16(kf0, qf[g][0], zero, 0, 0, 0);
        st[g] = __builtin_amdgcn_mfma_f32_16x16x32_bf16(kf1, qf[g][1], st[g], 0, 0, 0);
      }
      // p = exp2(s) (scale pre-folded into Q); pack bf16, one b64 write per g
#pragma unroll
      for (int g = 0; g < 2; ++g) {
        float p0 = __builtin_amdgcn_exp2f(st[g][0]);
        float p1 = __builtin_amdgcn_exp2f(st[g][1]);
        float p2 = __builtin_amdgcn_exp2f(st[g][2]);
        float p3 = __builtin_amdgcn_exp2f(st[g][3]);
        psg[g] += (p0 + p1) + (p2 + p3);
        uint2 pk;
        pk.x = __builtin_amdgcn_perm(__float_as_uint(p1), __float_as_uint(p0), 0x07060302);
        pk.y = __builtin_amdgcn_perm(__float_as_uint(p3), __float_as_uint(p2), 0x07060302);
        *(uint2*)&Ps[(w * 32 + g * 16 + lm) * LDP + jk * 16 + qd * 4] = pk;
      }
    }

    // same-wave LDS RAW (wave w only touches its own 32 Ps rows)
    asm volatile("s_waitcnt lgkmcnt(0)" ::: "memory");

    // O += P V
#pragma unroll
    for (int h2 = 0; h2 < 2; ++h2) {
      bf16x8 pf0 = *(const bf16x8*)&Ps[(w * 32 + lm) * LDP + h2 * 32 + qd * 8];
      bf16x8 pf1 = *(const bf16x8*)&Ps[(w * 32 + 16 + lm) * LDP + h2 * 32 + qd * 8];
#pragma unroll
      for (int jn = 0; jn < 4; ++jn) {
        bf16x8 vf = *(const bf16x8*)&Vs2[h2 * 2048 + (jn * 16 + lm) * 32 + cs];
        o[0][jn] = __builtin_amdgcn_mfma_f32_16x16x32_bf16(pf0, vf, o[0][jn], 0, 0, 0);
        o[1][jn] = __builtin_amdgcn_mfma_f32_16x16x32_bf16(pf1, vf, o[1][jn], 0, 0, 0);
      }
    }
  }

  // final row-sum reduce (over the 4 qd lane-groups) and normalize
  float l0 = psg[0], l1 = psg[1];
  l0 += __shfl_xor(l0, 16); l0 += __shfl_xor(l0, 32);
  l1 += __shfl_xor(l1, 16); l1 += __shfl_xor(l1, 32);
  if (qd == 0) {
    Ls[w * 32 + lm]      = l0;
    Ls[w * 32 + 16 + lm] = l1;
  }
  asm volatile("s_waitcnt lgkmcnt(0)" ::: "memory");

  const int b = bh >> 4, hh = bh & 15;
#pragma unroll
  for (int g = 0; g < 2; ++g)
#pragma unroll
    for (int r = 0; r < 4; ++r) {
      float inv = 1.0f / Ls[w * 32 + g * 16 + qd * 4 + r];
      int qrow = q0 + w * 32 + g * 16 + qd * 4 + r;
#pragma unroll
      for (int jn = 0; jn < 4; ++jn)
        out[(size_t)(b * SEQ + qrow) * DIM + hh * HD + jn * 16 + lm] = o[g][jn][r] * inv;
    }
}

extern "C" void kernel_launch(void* const* d_in, const int* in_sizes, int n_in,
                              void* d_out, int out_size, void* d_ws, size_t ws_size,
                              hipStream_t stream) {
  const float* x  = (const float*)d_in[0];
  const float* Wq = (const float*)d_in[1];
  const float* bq = (const float*)d_in[2];
  const float* Wk = (const float*)d_in[3];
  const float* bk = (const float*)d_in[4];
  const float* Wv = (const float*)d_in[5];
  const float* bv = (const float*)d_in[6];
  float* out = (float*)d_out;

  unsigned short* ws = (unsigned short*)d_ws;
  const size_t XE = (size_t)BATCH * SEQ * DIM;   // 8388608
  const size_t WE = (size_t)DIM * DIM;           // 1048576
  unsigned short* xb  = ws;
  unsigned short* wqb = xb + XE;
  unsigned short* wkb = wqb + WE;
  unsigned short* wvb = wkb + WE;
  unsigned short* qb  = wvb + WE;
  unsigned short* kb  = qb + XE;
  unsigned short* vb  = kb + XE;

  const int total_groups = (int)(XE / 8 + 3 * (WE / 8));   // 1441792
  cast_all_kernel<<<total_groups / 256, 256, 0, stream>>>(
      x, Wq, Wk, Wv, xb, wqb, wkb, wvb);

  dim3 gg(64, 8, 3);
  gemm_qkv<<<gg, 256, 0, stream>>>(xb, wqb, wkb, wvb, bq, bk, bv, qb, kb, vb);

  dim3 fg(SEQ / 128, BATCH * NH);
  flash_kernel<<<fg, 256, 0, stream>>>(qb, kb, vb, out);
}

// Round 6
// 245.542 us; speedup vs baseline: 1.1802x; 1.0104x over previous
//
#include <hip/hip_runtime.h>

typedef __bf16 bf16x8 __attribute__((ext_vector_type(8)));
typedef float f32x4 __attribute__((ext_vector_type(4)));

#define BATCH 4
#define SEQ   2048
#define DIM   1024
#define NH    16
#define HD    64
#define ECF   0.18033688f   // log2(e)/8 : folds 1/sqrt(64) into exp2

__device__ __forceinline__ unsigned short f2bf(float f) {
  union { float f; unsigned u; } v; v.f = f;
  unsigned u = v.u;
  u += 0x7FFF + ((u >> 16) & 1);   // round-to-nearest-even
  return (unsigned short)(u >> 16);
}

__device__ __forceinline__ void g2lds16(const unsigned short* g, unsigned short* l) {
  __builtin_amdgcn_global_load_lds(
      (const __attribute__((address_space(1))) unsigned int*)g,
      (__attribute__((address_space(3))) unsigned int*)l, 16, 0, 0);
}

// ------------- fused cast fp32 -> bf16 (x, Wq*EC, Wk, Wv) -------------
__global__ __launch_bounds__(256) void cast_all_kernel(
    const float* __restrict__ x,  const float* __restrict__ Wq,
    const float* __restrict__ Wk, const float* __restrict__ Wv,
    unsigned short* __restrict__ xb,  unsigned short* __restrict__ wqb,
    unsigned short* __restrict__ wkb, unsigned short* __restrict__ wvb) {
  const int XG = (BATCH * SEQ * DIM) / 8;   // 1048576
  const int WG = (DIM * DIM) / 8;           // 131072
  int i = blockIdx.x * 256 + threadIdx.x;
  const float* in; unsigned short* out; float sc = 1.0f; int off;
  if (i < XG)               { in = x;  out = xb;  off = i; }
  else if (i < XG + WG)     { in = Wq; out = wqb; off = i - XG; sc = ECF; }
  else if (i < XG + 2 * WG) { in = Wk; out = wkb; off = i - XG - WG; }
  else                      { in = Wv; out = wvb; off = i - XG - 2 * WG; }
  const float4* p = (const float4*)in + (size_t)off * 2;
  float4 a = p[0], b = p[1];
  unsigned short r[8];
  r[0] = f2bf(a.x * sc); r[1] = f2bf(a.y * sc); r[2] = f2bf(a.z * sc); r[3] = f2bf(a.w * sc);
  r[4] = f2bf(b.x * sc); r[5] = f2bf(b.y * sc); r[6] = f2bf(b.z * sc); r[7] = f2bf(b.w * sc);
  *(uint4*)&out[(size_t)off * 8] = *(uint4*)r;
}

// ---------------- fused QKV projection GEMM (unchanged from R5) -------
__global__ __launch_bounds__(256) void gemm_qkv(
    const unsigned short* __restrict__ A,
    const unsigned short* __restrict__ Wqp, const unsigned short* __restrict__ Wkp,
    const unsigned short* __restrict__ Wvp,
    const float* __restrict__ bqp, const float* __restrict__ bkp,
    const float* __restrict__ bvp,
    unsigned short* __restrict__ oq, unsigned short* __restrict__ ok,
    unsigned short* __restrict__ ov) {
  __shared__ unsigned short As[128 * 32];
  __shared__ unsigned short Bs[128 * 32];
  const int z = blockIdx.z;
  const unsigned short* W = (z == 0) ? Wqp : (z == 1) ? Wkp : Wvp;
  const float* bias        = (z == 0) ? bqp : (z == 1) ? bkp : bvp;
  unsigned short* outp     = (z == 0) ? oq  : (z == 1) ? ok  : ov;
  const float bsc          = (z == 0) ? ECF : 1.0f;   // bq scaled like Wq
  const int mode = (z == 2) ? 1 : 0;

  const int tid  = threadIdx.x;
  const int wave = tid >> 6;
  const int lane = tid & 63;
  const int lm   = lane & 15;
  const int qd   = lane >> 4;
  const int m0 = blockIdx.x * 128;
  const int n0 = blockIdx.y * 128;
  const int wm = (wave >> 1) * 64;
  const int wn = (wave & 1) * 64;

  const f32x4 zero = {0.f, 0.f, 0.f, 0.f};
  f32x4 acc[4][4];
#pragma unroll
  for (int i = 0; i < 4; ++i)
#pragma unroll
    for (int j = 0; j < 4; ++j) acc[i][j] = zero;

  const int srow = tid >> 2;                               // 0..63
  const int scol = (((tid & 3) ^ ((tid >> 3) & 3))) * 8;   // swizzled source chunk
  const int cs   = (qd ^ ((lm >> 1) & 3)) * 8;             // swizzled read chunk

  for (int kt = 0; kt < DIM; kt += 32) {
    __syncthreads();
    g2lds16(&A[(size_t)(m0 + srow) * DIM + kt + scol],       &As[(size_t)tid * 8]);
    g2lds16(&A[(size_t)(m0 + 64 + srow) * DIM + kt + scol],  &As[2048 + (size_t)tid * 8]);
    g2lds16(&W[(size_t)(n0 + srow) * DIM + kt + scol],       &Bs[(size_t)tid * 8]);
    g2lds16(&W[(size_t)(n0 + 64 + srow) * DIM + kt + scol],  &Bs[2048 + (size_t)tid * 8]);
    __syncthreads();

    bf16x8 af[4], bfr[4];
#pragma unroll
    for (int i = 0; i < 4; ++i) af[i]  = *(const bf16x8*)&As[(wm + i * 16 + lm) * 32 + cs];
#pragma unroll
    for (int j = 0; j < 4; ++j) bfr[j] = *(const bf16x8*)&Bs[(wn + j * 16 + lm) * 32 + cs];
#pragma unroll
    for (int i = 0; i < 4; ++i)
#pragma unroll
      for (int j = 0; j < 4; ++j)
        acc[i][j] = __builtin_amdgcn_mfma_f32_16x16x32_bf16(af[i], bfr[j], acc[i][j], 0, 0, 0);
  }

#pragma unroll
  for (int j = 0; j < 4; ++j) {
    int col = n0 + wn + j * 16 + lm;       // n index
    float bb = bias[col] * bsc;
    int h = col >> 6, hd = col & 63;
#pragma unroll
    for (int i = 0; i < 4; ++i) {
      int rowb = m0 + wm + i * 16 + qd * 4;   // base m index (r=0)
      int b = rowb >> 11, s = rowb & 2047;
      if (mode == 0) {
#pragma unroll
        for (int r = 0; r < 4; ++r) {
          float v = acc[i][j][r] + bb;
          outp[((size_t)(b * NH + h) * SEQ + (s + r)) * HD + hd] = f2bf(v);
        }
      } else {
        unsigned short pk[4];
#pragma unroll
        for (int r = 0; r < 4; ++r) pk[r] = f2bf(acc[i][j][r] + bb);
        size_t idx = ((size_t)(b * NH + h) * HD + hd) * SEQ + s;
        *(uint2*)&outp[idx] = *(uint2*)pk;
      }
    }
  }
}

// ---------------- flash attention: 2 waves, 64 q-rows/wave -----------
// Q (pre-scaled),K: [bh,s,hd] bf16. V: [bh,hd,s] bf16. out: [b,s,h*hd] f32.
// DS-bound analysis (R5): K/V tile reads are per-wave invariant in q-rows,
// so 64 q/wave halves DS traffic per unit work. Ps: stride 64 + XOR-chunk
// swizzle (chunk ^ (row&7)) -> conflict-free reads, 2-way (free) writes.
__global__ __launch_bounds__(128, 2) void flash_kernel(
    const unsigned short* __restrict__ Qw, const unsigned short* __restrict__ Kw,
    const unsigned short* __restrict__ Vw, float* __restrict__ out) {
  __shared__ unsigned short Ks2[2 * 64 * 32];   // [hd_half][key][32] swizzled
  __shared__ unsigned short Vs2[2 * 64 * 32];   // [key_half][hd][32] swizzled
  __shared__ unsigned short Ps[128 * 64];       // [qrow][key] chunk-swizzled
  __shared__ float Ls[128];

  const int tid  = threadIdx.x;   // 0..127
  const int w    = tid >> 6;      // wave 0..1
  const int lane = tid & 63;
  const int lm   = lane & 15;
  const int qd   = lane >> 4;
  const int bh   = blockIdx.y;
  const int q0   = blockIdx.x * 128;

  const unsigned short* Qbase = Qw + (size_t)bh * (SEQ * HD);
  const unsigned short* Kbase = Kw + (size_t)bh * (SEQ * HD);
  const unsigned short* Vbase = Vw + (size_t)bh * (HD * SEQ);

  // Q fragments in registers: 64 rows per wave (4 groups of 16)
  bf16x8 qf[4][2];
#pragma unroll
  for (int g = 0; g < 4; ++g)
#pragma unroll
    for (int h = 0; h < 2; ++h)
      qf[g][h] = *(const bf16x8*)&Qbase[(size_t)(q0 + w * 64 + g * 16 + lm) * HD + h * 32 + qd * 8];

  const f32x4 zero = {0.f, 0.f, 0.f, 0.f};
  f32x4 o[4][4];
#pragma unroll
  for (int g = 0; g < 4; ++g)
#pragma unroll
    for (int jn = 0; jn < 4; ++jn) o[g][jn] = zero;
  float psg[4] = {0.f, 0.f, 0.f, 0.f};

  // staging: 256 16B-chunks per tensor-half pair; thread t fills chunks t, t+128
  const int c0 = tid, c1 = tid + 128;
  const int r0 = c0 >> 2, p0s = ((c0 & 3) ^ ((c0 >> 3) & 3)) * 8;
  const int r1 = c1 >> 2, p1s = ((c1 & 3) ^ ((c1 >> 3) & 3)) * 8;

  const int cs  = (qd ^ ((lm >> 1) & 3)) * 8;   // K/V swizzled read chunk
  const int pk_key = lm & 7;                     // Ps swizzle key

  for (int kt = 0; kt < SEQ / 64; ++kt) {
    const int k0 = kt * 64;
    __syncthreads();
    g2lds16(&Kbase[(size_t)(k0 + r0) * HD + p0s],      &Ks2[(size_t)c0 * 8]);
    g2lds16(&Kbase[(size_t)(k0 + r1) * HD + p1s],      &Ks2[(size_t)c1 * 8]);
    g2lds16(&Kbase[(size_t)(k0 + r0) * HD + 32 + p0s], &Ks2[2048 + (size_t)c0 * 8]);
    g2lds16(&Kbase[(size_t)(k0 + r1) * HD + 32 + p1s], &Ks2[2048 + (size_t)c1 * 8]);
    g2lds16(&Vbase[(size_t)r0 * SEQ + k0 + p0s],       &Vs2[(size_t)c0 * 8]);
    g2lds16(&Vbase[(size_t)r1 * SEQ + k0 + p1s],       &Vs2[(size_t)c1 * 8]);
    g2lds16(&Vbase[(size_t)r0 * SEQ + k0 + 32 + p0s],  &Vs2[2048 + (size_t)c0 * 8]);
    g2lds16(&Vbase[(size_t)r1 * SEQ + k0 + 32 + p1s],  &Vs2[2048 + (size_t)c1 * 8]);
    __syncthreads();

    // S^T = K Q^T : rows key=jk*16+qd*4+r, cols qrow=g*16+lm
#pragma unroll
    for (int jk = 0; jk < 4; ++jk) {
      bf16x8 kf0 = *(const bf16x8*)&Ks2[(jk * 16 + lm) * 32 + cs];
      bf16x8 kf1 = *(const bf16x8*)&Ks2[2048 + (jk * 16 + lm) * 32 + cs];
      f32x4 st[4];
#pragma unroll
      for (int g = 0; g < 4; ++g) {
        st[g] = __builtin_amdgcn_mfma_f32_16x16x32_bf16(kf0, qf[g][0], zero, 0, 0, 0);
        st[g] = __builtin_amdgcn_mfma_f32_16x16x32_bf16(kf1, qf[g][1], st[g], 0, 0, 0);
      }
#pragma unroll
      for (int g = 0; g < 4; ++g) {
        float p0 = __builtin_amdgcn_exp2f(st[g][0]);
        float p1 = __builtin_amdgcn_exp2f(st[g][1]);
        float p2 = __builtin_amdgcn_exp2f(st[g][2]);
        float p3 = __builtin_amdgcn_exp2f(st[g][3]);
        psg[g] += (p0 + p1) + (p2 + p3);
        uint2 pk;
        pk.x = __builtin_amdgcn_perm(__float_as_uint(p1), __float_as_uint(p0), 0x07060302);
        pk.y = __builtin_amdgcn_perm(__float_as_uint(p3), __float_as_uint(p2), 0x07060302);
        // logical chunk 2jk+(qd>>1), swizzled by row&7 = lm&7
        int sw = (2 * jk + (qd >> 1)) ^ pk_key;
        *(uint2*)&Ps[(w * 64 + g * 16 + lm) * 64 + sw * 8 + (qd & 1) * 4] = pk;
      }
    }

    // same-wave LDS RAW (wave w only touches its own 64 Ps rows)
    asm volatile("s_waitcnt lgkmcnt(0)" ::: "memory");

    // O += P V
#pragma unroll
    for (int h2 = 0; h2 < 2; ++h2) {
      bf16x8 pf[4];
#pragma unroll
      for (int g = 0; g < 4; ++g) {
        int sw = (h2 * 4 + qd) ^ pk_key;
        pf[g] = *(const bf16x8*)&Ps[(w * 64 + g * 16 + lm) * 64 + sw * 8];
      }
#pragma unroll
      for (int jn = 0; jn < 4; ++jn) {
        bf16x8 vf = *(const bf16x8*)&Vs2[h2 * 2048 + (jn * 16 + lm) * 32 + cs];
#pragma unroll
        for (int g = 0; g < 4; ++g)
          o[g][jn] = __builtin_amdgcn_mfma_f32_16x16x32_bf16(pf[g], vf, o[g][jn], 0, 0, 0);
      }
    }
  }

  // final row-sum reduce (over the 4 qd lane-groups) and normalize
#pragma unroll
  for (int g = 0; g < 4; ++g) {
    float l = psg[g];
    l += __shfl_xor(l, 16); l += __shfl_xor(l, 32);
    if (qd == 0) Ls[w * 64 + g * 16 + lm] = l;
  }
  asm volatile("s_waitcnt lgkmcnt(0)" ::: "memory");

  const int b = bh >> 4, hh = bh & 15;
#pragma unroll
  for (int g = 0; g < 4; ++g)
#pragma unroll
    for (int r = 0; r < 4; ++r) {
      float inv = 1.0f / Ls[w * 64 + g * 16 + qd * 4 + r];
      int qrow = q0 + w * 64 + g * 16 + qd * 4 + r;
#pragma unroll
      for (int jn = 0; jn < 4; ++jn)
        out[(size_t)(b * SEQ + qrow) * DIM + hh * HD + jn * 16 + lm] = o[g][jn][r] * inv;
    }
}

extern "C" void kernel_launch(void* const* d_in, const int* in_sizes, int n_in,
                              void* d_out, int out_size, void* d_ws, size_t ws_size,
                              hipStream_t stream) {
  const float* x  = (const float*)d_in[0];
  const float* Wq = (const float*)d_in[1];
  const float* bq = (const float*)d_in[2];
  const float* Wk = (const float*)d_in[3];
  const float* bk = (const float*)d_in[4];
  const float* Wv = (const float*)d_in[5];
  const float* bv = (const float*)d_in[6];
  float* out = (float*)d_out;

  unsigned short* ws = (unsigned short*)d_ws;
  const size_t XE = (size_t)BATCH * SEQ * DIM;   // 8388608
  const size_t WE = (size_t)DIM * DIM;           // 1048576
  unsigned short* xb  = ws;
  unsigned short* wqb = xb + XE;
  unsigned short* wkb = wqb + WE;
  unsigned short* wvb = wkb + WE;
  unsigned short* qb  = wvb + WE;
  unsigned short* kb  = qb + XE;
  unsigned short* vb  = kb + XE;

  const int total_groups = (int)(XE / 8 + 3 * (WE / 8));   // 1441792
  cast_all_kernel<<<total_groups / 256, 256, 0, stream>>>(
      x, Wq, Wk, Wv, xb, wqb, wkb, wvb);

  dim3 gg(64, 8, 3);
  gemm_qkv<<<gg, 256, 0, stream>>>(xb, wqb, wkb, wvb, bq, bk, bv, qb, kb, vb);

  dim3 fg(SEQ / 128, BATCH * NH);
  flash_kernel<<<fg, 128, 0, stream>>>(qb, kb, vb, out);
}